// Round 15
// baseline (324.391 us; speedup 1.0000x reference)
//
#include <hip/hip_runtime.h>

#define NPTS 8192
#define NB 4
#define CH 64
#define KNN 16
#define QPW 4      // queries per wave (register-blocked)
#define CAP 256    // survivor cap per query (expected ~20-40; >=16 guaranteed)

using bf16x8 = __attribute__((ext_vector_type(8))) __bf16;
using us8    = __attribute__((ext_vector_type(8))) unsigned short;
using f32x4  = __attribute__((ext_vector_type(4))) float;

__device__ __forceinline__ float bf2f(unsigned short u) {
    return __uint_as_float(((unsigned)u) << 16);
}
__device__ __forceinline__ unsigned short f2bf(float f) {
    unsigned u = __float_as_uint(f);
    u += 0x7fffu + ((u >> 16) & 1u);
    return (unsigned short)(u >> 16);
}

// split 8 f32 into hi/lo bf16 fragments: x = hi + lo to ~16 extra mantissa bits
__device__ __forceinline__ void split8(const float* x, bf16x8& hi, bf16x8& lo) {
    us8 h, l;
#pragma unroll
    for (int j = 0; j < 8; ++j) {
        const unsigned short hb = f2bf(x[j]);
        h[j] = hb;
        l[j] = f2bf(x[j] - bf2f(hb));
    }
    hi = __builtin_bit_cast(bf16x8, h);
    lo = __builtin_bit_cast(bf16x8, l);
}

// lexicographic (d,i) compare: true if (dB,iB) < (dA,iA)
__device__ __forceinline__ bool lex_lt(float dB, int iB, float dA, int iA) {
    return (dB < dA) || ((dB == dA) && (iB < iA));
}

// ---------------- Kernel 0: pack points as {x,y,z,sq} (sq formula = reference path) --
__global__ __launch_bounds__(256) void pack_kernel(const float* __restrict__ pts,
                                                   float4* __restrict__ pts4) {
    const int i = blockIdx.x * 256 + threadIdx.x;   // 0..32767
    const float x = pts[i * 3 + 0];
    const float y = pts[i * 3 + 1];
    const float z = pts[i * 3 + 2];
    pts4[i] = make_float4(x, y, z, (x * x + y * y) + z * z);
}

// ---------------- Kernel 1: 4-query-per-wave KNN, two-pass threshold ----------------
// r13-proven selection logic. New: Pass B wave-uniform pre-gate — one ballot on
// any_qq(d<=U); when zero the per-query ballot/compaction is a provable no-op and
// is skipped. Admission set / buffer order / rank epilogue bit-identical.
__global__ __launch_bounds__(256) void knn_wave_kernel(const float4* __restrict__ pts4,
                                                       int* __restrict__ idx_out) {
    __shared__ float s_bd[16][CAP];
    __shared__ int   s_bi[16][CAP];
    __shared__ float s_mins[16][64];
    __shared__ float s_U[16];

    const int lane = threadIdx.x & 63;
    const int w    = threadIdx.x >> 6;
    const int qbase = (blockIdx.x * 4 + w) * QPW;     // 16 queries per block
    const int b = qbase >> 13;                        // 4 queries share one batch
    const int n0 = qbase & (NPTS - 1);
    const float4* pb4 = pts4 + (size_t)b * NPTS;

    float4 qp[QPW];
#pragma unroll
    for (int qq = 0; qq < QPW; ++qq) qp[qq] = pb4[n0 + qq];

    // ---- Pass A: per-lane min distance, 4 queries ----
    float mn[QPW];
#pragma unroll
    for (int qq = 0; qq < QPW; ++qq) mn[qq] = 3.4e38f;
#pragma unroll 4
    for (int t = 0; t < NPTS / 64; ++t) {
        const float4 v = pb4[t * 64 + lane];
#pragma unroll
        for (int qq = 0; qq < QPW; ++qq) {
            float dot = qp[qq].x * v.x;
            dot = fmaf(qp[qq].y, v.y, dot);
            dot = fmaf(qp[qq].z, v.z, dot);
            const float d = fmaf(dot, -2.0f, qp[qq].w + v.w);  // identical rounding
            mn[qq] = fminf(mn[qq], d);
        }
    }
#pragma unroll
    for (int qq = 0; qq < QPW; ++qq) s_mins[w * QPW + qq][lane] = mn[qq];
    __syncthreads();
#pragma unroll
    for (int qq = 0; qq < QPW; ++qq) {
        const float m = mn[qq];
        int rank = 0;
        for (int j = 0; j < 64; ++j) {
            const float vv = s_mins[w * QPW + qq][j];
            rank += ((vv < m) || (vv == m && j < lane)) ? 1 : 0;
        }
        if (rank == 15) s_U[w * QPW + qq] = m;   // exactly one lane has rank 15
    }
    __syncthreads();
    float U[QPW];
#pragma unroll
    for (int qq = 0; qq < QPW; ++qq) U[qq] = s_U[w * QPW + qq] + 1e-4f;

    // ---- Pass B: gated compaction, 4 queries, wave-uniform pre-gate ----
    int cnt[QPW] = {0, 0, 0, 0};
#pragma unroll 2
    for (int t = 0; t < NPTS / 64; ++t) {
        const int c = t * 64 + lane;
        const float4 v = pb4[c];
        float d[QPW];
        bool any = false;
#pragma unroll
        for (int qq = 0; qq < QPW; ++qq) {
            float dot = qp[qq].x * v.x;
            dot = fmaf(qp[qq].y, v.y, dot);
            dot = fmaf(qp[qq].z, v.z, dot);
            d[qq] = fmaf(dot, -2.0f, qp[qq].w + v.w);
            any = any || (d[qq] <= U[qq]);
        }
        if (__any(any)) {                        // uniform; skipped iters are no-ops
#pragma unroll
            for (int qq = 0; qq < QPW; ++qq) {
                const bool adm = d[qq] <= U[qq];
                const unsigned long long mask = __ballot(adm);
                if (mask) {
                    const int add = __popcll(mask);
                    if (adm) {
                        const int off = cnt[qq] + (int)__popcll(mask & ((1ull << lane) - 1ull));
                        if (off < CAP) {
                            s_bd[w * QPW + qq][off] = d[qq];
                            s_bi[w * QPW + qq][off] = c;
                        }
                    }
                    cnt[qq] = min(cnt[qq] + add, CAP);
                }
            }
        }
    }
    __syncthreads();

    // ---- rank selection: survivor j's lex rank among its query's survivors ----
#pragma unroll
    for (int qq = 0; qq < QPW; ++qq) {
        const int qi = w * QPW + qq;
        const int cn = cnt[qq];
        for (int j = lane; j < cn; j += 64) {
            const float dj = s_bd[qi][j];
            const int   ij = s_bi[qi][j];
            int rk = 0;
            for (int k = 0; k < cn; ++k)
                rk += lex_lt(s_bd[qi][k], s_bi[qi][k], dj, ij) ? 1 : 0;
            if (rk < KNN) idx_out[(size_t)(qbase + qq) * KNN + rk] = ij;
        }
    }
}

// ---------------- Kernel 2: MFMA agg — one wave per point, hi/lo bf16 (r11-proven) ----
#define MIDP 132   // s_mid leading-dim pad: 128 -> 132 breaks bank-aligned row stride
__global__ __launch_bounds__(256) void agg_kernel(
    const float* __restrict__ pts,
    const float* __restrict__ feat,
    const float* __restrict__ w_geom,
    const float* __restrict__ g1, const float* __restrict__ b1,
    const float* __restrict__ m1, const float* __restrict__ v1,
    const float* __restrict__ w_sem,
    const float* __restrict__ g2, const float* __restrict__ b2,
    const float* __restrict__ m2, const float* __restrict__ v2,
    const float* __restrict__ w_fuse,
    const float* __restrict__ g3, const float* __restrict__ b3,
    const float* __restrict__ m3, const float* __restrict__ v3,
    const int* __restrict__ knn_idx,
    float* __restrict__ outp) {

    __shared__ alignas(16) unsigned short s_wsemB[8192];    // 16 frags x 64 lanes x 8 bf16
    __shared__ alignas(16) unsigned short s_wfuseB[8192];
    __shared__ float s_wg[6][64];
    __shared__ float s_s1[64], s_b1[64], s_s2[64], s_b2[64], s_s3[64], s_b3[64];
    __shared__ alignas(16) float s_mid[4][16][MIDP];
    __shared__ float s_pm[4][4][64];
    __shared__ alignas(16) float s_ctrf[4][64];
    __shared__ float s_gd[4][16][4];
    __shared__ int   s_nidx[4][16];
    __shared__ float s_ctrp[4][4];

    const int tid = threadIdx.x;
    const int w = tid >> 6, lane = tid & 63;
    const int r = lane & 15, qd = lane >> 4;

    for (int e = tid; e < 1024; e += 256) {          // e = (kc*4+n0)*64 + ln
        const int ln = e & 63;
        const int o = ((e >> 6) & 3) * 16 + (ln & 15);
        const int c = (e >> 8) * 32 + (ln >> 4) * 8;
        unsigned short ts[8], tf[8];
#pragma unroll
        for (int j = 0; j < 8; ++j) {
            ts[j] = f2bf(w_sem [o * 128 + c + j]);
            tf[j] = f2bf(w_fuse[o * 128 + c + j]);
        }
        *(uint4*)&s_wsemB [e * 8] = *(uint4*)ts;
        *(uint4*)&s_wfuseB[e * 8] = *(uint4*)tf;
    }
    for (int e = tid; e < 384; e += 256) {
        const int c = e >> 6, o = e & 63;
        s_wg[c][o] = w_geom[o * 6 + c];
    }
    if (tid < 64) {
        float s;
        s = g1[tid] / sqrtf(v1[tid] + 1e-5f);
        s_s1[tid] = s; s_b1[tid] = b1[tid] - m1[tid] * s;
        s = g2[tid] / sqrtf(v2[tid] + 1e-5f);
        s_s2[tid] = s; s_b2[tid] = b2[tid] - m2[tid] * s;
        s = g3[tid] / sqrtf(v3[tid] + 1e-5f);
        s_s3[tid] = s; s_b3[tid] = b3[tid] - m3[tid] * s;
    }
    __syncthreads();

    const f32x4 zero = {0.f, 0.f, 0.f, 0.f};

    for (int i = 0; i < 4; ++i) {
        const int pv = blockIdx.x * 16 + w * 4 + i;
        const int b = pv >> 13, n = pv & (NPTS - 1);
        const long pbase = (long)b * NPTS + n;

        if (lane < 16) s_nidx[w][lane] = knn_idx[pbase * KNN + lane];
        s_ctrf[w][lane] = feat[pbase * CH + lane];
        if (lane < 3) s_ctrp[w][lane] = pts[pbase * 3 + lane];
        __syncthreads();                                       // B1

        if (lane < 16) {
            const long nb = (long)b * NPTS + s_nidx[w][lane];
            s_gd[w][lane][0] = pts[nb * 3 + 0] - s_ctrp[w][0];
            s_gd[w][lane][1] = pts[nb * 3 + 1] - s_ctrp[w][1];
            s_gd[w][lane][2] = pts[nb * 3 + 2] - s_ctrp[w][2];
        }

        bf16x8 ah[4], al[4];
        {
            float xs[8];
#pragma unroll
            for (int kc = 0; kc < 2; ++kc) {
#pragma unroll
                for (int j = 0; j < 8; ++j) xs[j] = s_ctrf[w][kc * 32 + qd * 8 + j];
                split8(xs, ah[kc], al[kc]);
            }
            const long nb = (long)b * NPTS + s_nidx[w][r];
            const float* fp = feat + nb * CH;
#pragma unroll
            for (int kc = 0; kc < 2; ++kc) {
                const int base = kc * 32 + qd * 8;
                const float4 v0 = *(const float4*)(fp + base);
                const float4 v1 = *(const float4*)(fp + base + 4);
                xs[0] = v0.x - s_ctrf[w][base + 0];
                xs[1] = v0.y - s_ctrf[w][base + 1];
                xs[2] = v0.z - s_ctrf[w][base + 2];
                xs[3] = v0.w - s_ctrf[w][base + 3];
                xs[4] = v1.x - s_ctrf[w][base + 4];
                xs[5] = v1.y - s_ctrf[w][base + 5];
                xs[6] = v1.z - s_ctrf[w][base + 6];
                xs[7] = v1.w - s_ctrf[w][base + 7];
                split8(xs, ah[2 + kc], al[2 + kc]);
            }
        }
        f32x4 acc[4] = {zero, zero, zero, zero};
#pragma unroll
        for (int kc = 0; kc < 4; ++kc) {
#pragma unroll
            for (int n0 = 0; n0 < 4; ++n0) {
                const bf16x8 bw = *(const bf16x8*)&s_wsemB[((kc * 4 + n0) * 64 + lane) * 8];
                acc[n0] = __builtin_amdgcn_mfma_f32_16x16x32_bf16(ah[kc], bw, acc[n0], 0, 0, 0);
                acc[n0] = __builtin_amdgcn_mfma_f32_16x16x32_bf16(al[kc], bw, acc[n0], 0, 0, 0);
            }
        }
#pragma unroll
        for (int n0 = 0; n0 < 4; ++n0) {
            const int nn = n0 * 16 + r;
            const float sv = s_s2[nn], bv = s_b2[nn];
#pragma unroll
            for (int reg = 0; reg < 4; ++reg) {
                s_mid[w][qd * 4 + reg][64 + nn] = fmaxf(fmaf(acc[n0][reg], sv, bv), 0.f);
            }
        }
        __syncthreads();                                       // B2 (s_gd ready)

        {
            const int o = lane;
            float cg = s_ctrp[w][0] * s_wg[0][o];
            cg = fmaf(s_ctrp[w][1], s_wg[1][o], cg);
            cg = fmaf(s_ctrp[w][2], s_wg[2][o], cg);
            const float s1o = s_s1[o], b1o = s_b1[o];
#pragma unroll
            for (int r2 = 0; r2 < 16; ++r2) {
                float g = cg;
                g = fmaf(s_gd[w][r2][0], s_wg[3][o], g);
                g = fmaf(s_gd[w][r2][1], s_wg[4][o], g);
                g = fmaf(s_gd[w][r2][2], s_wg[5][o], g);
                s_mid[w][r2][o] = fmaxf(fmaf(g, s1o, b1o), 0.f);
            }
        }
        __syncthreads();                                       // B3 (mid complete)

        bf16x8 fh[4], fl[4];
        {
            float xs[8];
#pragma unroll
            for (int kc = 0; kc < 4; ++kc) {
                const float* mp = &s_mid[w][r][kc * 32 + qd * 8];
#pragma unroll
                for (int j = 0; j < 8; ++j) xs[j] = mp[j];
                split8(xs, fh[kc], fl[kc]);
            }
        }
        f32x4 acc2[4] = {zero, zero, zero, zero};
#pragma unroll
        for (int kc = 0; kc < 4; ++kc) {
#pragma unroll
            for (int n0 = 0; n0 < 4; ++n0) {
                const bf16x8 bw = *(const bf16x8*)&s_wfuseB[((kc * 4 + n0) * 64 + lane) * 8];
                acc2[n0] = __builtin_amdgcn_mfma_f32_16x16x32_bf16(fh[kc], bw, acc2[n0], 0, 0, 0);
                acc2[n0] = __builtin_amdgcn_mfma_f32_16x16x32_bf16(fl[kc], bw, acc2[n0], 0, 0, 0);
            }
        }
#pragma unroll
        for (int n0 = 0; n0 < 4; ++n0) {
            const int nn = n0 * 16 + r;
            const float sv = s_s3[nn], bv = s_b3[nn];
            float mx = 0.f;   // relu outputs >= 0
#pragma unroll
            for (int reg = 0; reg < 4; ++reg)
                mx = fmaxf(mx, fmaxf(fmaf(acc2[n0][reg], sv, bv), 0.f));
            s_pm[w][qd][nn] = mx;
        }
        __syncthreads();                                       // B4
        {
            const int o = lane;
            const float rv = fmaxf(fmaxf(s_pm[w][0][o], s_pm[w][1][o]),
                                   fmaxf(s_pm[w][2][o], s_pm[w][3][o]));
            outp[pbase * CH + o] = rv;
        }
        __syncthreads();                                       // B5 (WAR across iters)
    }
}

extern "C" void kernel_launch(void* const* d_in, const int* in_sizes, int n_in,
                              void* d_out, int out_size, void* d_ws, size_t ws_size,
                              hipStream_t stream) {
    (void)in_sizes; (void)n_in; (void)out_size; (void)ws_size;
    const float* pts    = (const float*)d_in[0];
    const float* feat   = (const float*)d_in[1];
    const float* w_geom = (const float*)d_in[2];
    const float* g1     = (const float*)d_in[3];
    const float* b1     = (const float*)d_in[4];
    const float* m1     = (const float*)d_in[5];
    const float* v1     = (const float*)d_in[6];
    const float* w_sem  = (const float*)d_in[7];
    const float* g2     = (const float*)d_in[8];
    const float* b2     = (const float*)d_in[9];
    const float* m2     = (const float*)d_in[10];
    const float* v2     = (const float*)d_in[11];
    const float* w_fuse = (const float*)d_in[12];
    const float* g3     = (const float*)d_in[13];
    const float* b3     = (const float*)d_in[14];
    const float* m3     = (const float*)d_in[15];
    const float* v3     = (const float*)d_in[16];

    int*    idx_final = (int*)d_ws;                             // 2 MB @ 0
    float4* pts4      = (float4*)((char*)d_ws + (4ull << 20));  // 512 KB @ 4MB

    pack_kernel<<<dim3(NB * NPTS / 256), dim3(256), 0, stream>>>(pts, pts4);
    knn_wave_kernel<<<dim3(NB * NPTS / 16), dim3(256), 0, stream>>>(pts4, idx_final);

    agg_kernel<<<dim3(2048), dim3(256), 0, stream>>>(
        pts, feat, w_geom, g1, b1, m1, v1, w_sem, g2, b2, m2, v2,
        w_fuse, g3, b3, m3, v3, idx_final, (float*)d_out);
}